// Round 11
// baseline (469.490 us; speedup 1.0000x reference)
//
#include <hip/hip_runtime.h>

#define D 128
#define NGRAPH 64
#define NACT 40
#define SCAN_TPB 256
#define SCAN_EPT 8
#define SCAN_CHUNK 2048
#define GNODES 8
#define POOL_CHUNK 64

typedef __attribute__((ext_vector_type(8))) short bf16x8;
typedef __attribute__((ext_vector_type(4))) float f32x4;
typedef __attribute__((ext_vector_type(8))) unsigned short us8;

__device__ inline unsigned short f2b(float f) {            // fp32 -> bf16 RNE
    unsigned u = __float_as_uint(f);
    return (unsigned short)((u + 0x7FFFu + ((u >> 16) & 1u)) >> 16);
}
__device__ inline float b2f(unsigned short h) {
    return __uint_as_float(((unsigned)h) << 16);
}

// ---- fused fp32 pools: y=0 init->ctx, y=1 lead->ctx, y=2 inputs->hg0 (+bf16 conv) ----
__global__ void pool3_kernel(const float* __restrict__ f0, const int* __restrict__ g0, float* o0,
                             const float* __restrict__ f1, const int* __restrict__ g1, float* o1,
                             const float* __restrict__ f2, const int* __restrict__ g2, float* o2,
                             unsigned short* __restrict__ Hbf, int n_nodes) {
    const float* feats; const int* gids; float* out; bool conv = false;
    if (blockIdx.y == 0)      { feats = f0; gids = g0; out = o0; }
    else if (blockIdx.y == 1) { feats = f1; gids = g1; out = o1; }
    else                      { feats = f2; gids = g2; out = o2; conv = true; }
    int t = threadIdx.x;
    int start = blockIdx.x * POOL_CHUNK;
    int end = start + POOL_CHUNK;
    if (end > n_nodes) end = n_nodes;
    if (start >= end) return;
    int cur = gids[start];
    float acc = 0.f;
    int r = start;
    while (r < end) {
        if (r + 3 < end && gids[r] == cur && gids[r + 3] == cur) {
            float v0 = feats[(size_t)r * D + t];
            float v1 = feats[(size_t)(r + 1) * D + t];
            float v2 = feats[(size_t)(r + 2) * D + t];
            float v3 = feats[(size_t)(r + 3) * D + t];
            if (conv) {
                Hbf[(size_t)r * D + t]       = f2b(v0);
                Hbf[(size_t)(r + 1) * D + t] = f2b(v1);
                Hbf[(size_t)(r + 2) * D + t] = f2b(v2);
                Hbf[(size_t)(r + 3) * D + t] = f2b(v3);
            }
            acc += (v0 + v1) + (v2 + v3);
            r += 4;
            continue;
        }
        int g = gids[r];
        if (g != cur) { atomicAdd(&out[cur * D + t], acc); acc = 0.f; cur = g; }
        float v = feats[(size_t)r * D + t];
        if (conv) Hbf[(size_t)r * D + t] = f2b(v);
        acc += v;
        ++r;
    }
    atomicAdd(&out[cur * D + t], acc);
}

// ---- X = H @ W via bf16 MFMA; extra blocks past mm_blocks do ctxw ----
// A frag: row=lane&15, k=(lane>>4)*8+[0..7]; B frag from W^T; C/D: col=lane&15,
// row=(lane>>4)*4+reg (m89/m92 verified layouts).
__global__ __launch_bounds__(256) void mm_ctxw_kernel(
        const unsigned short* __restrict__ Hb, const unsigned short* __restrict__ WT,
        unsigned short* __restrict__ X,
        const float* __restrict__ hg, const float* __restrict__ ctx,
        const float* __restrict__ Wf, const float* __restrict__ bias,
        float* __restrict__ ctxgW, int n_rows, int mm_blocks) {
    __shared__ unsigned short aT[64 * 136];    // 17.4 KB
    __shared__ unsigned short bT[128 * 136];   // 34.8 KB
    __shared__ float row2[2][D];               // 1 KB (ctxw branch)
    int t = threadIdx.x;

    if ((int)blockIdx.x >= mm_blocks) {        // ---- ctxw: 2 graphs per block ----
        int bb = blockIdx.x - mm_blocks;
        int half = t >> 7;
        int g = bb * 2 + half;
        int tc = t & 127;
        row2[half][tc] = hg[g * D + tc] + ctx[g * D + tc];
        __syncthreads();
        float acc = bias[tc];
#pragma unroll 4
        for (int k = 0; k < D; ++k) acc = fmaf(row2[half][k], Wf[k * D + tc], acc);
        ctxgW[g * D + tc] = acc;
        return;
    }

    int r0 = blockIdx.x * 64;
    for (int i = t; i < 1024; i += 256) {      // stage A: 64x128 bf16
        int r = i >> 4, kq = i & 15;
        us8 v = {0, 0, 0, 0, 0, 0, 0, 0};
        if (r0 + r < n_rows) v = *(const us8*)(Hb + (size_t)(r0 + r) * D + kq * 8);
        *(us8*)&aT[r * 136 + kq * 8] = v;
    }
    for (int i = t; i < 2048; i += 256) {      // stage B: 128x128 bf16 (W^T)
        int n = i >> 4, kq = i & 15;
        *(us8*)&bT[n * 136 + kq * 8] = *(const us8*)(WT + n * D + kq * 8);
    }
    __syncthreads();

    int lane = t & 63;
    int rbase = (t >> 6) * 16;
    int arow = lane & 15, kgrp = lane >> 4;
    f32x4 acc[8];
#pragma unroll
    for (int i = 0; i < 8; ++i) acc[i] = (f32x4){0.f, 0.f, 0.f, 0.f};

#pragma unroll
    for (int kc = 0; kc < 4; ++kc) {
        bf16x8 a = *(bf16x8*)&aT[(rbase + arow) * 136 + kc * 32 + kgrp * 8];
#pragma unroll
        for (int nt = 0; nt < 8; ++nt) {
            bf16x8 b = *(bf16x8*)&bT[(nt * 16 + arow) * 136 + kc * 32 + kgrp * 8];
            acc[nt] = __builtin_amdgcn_mfma_f32_16x16x32_bf16(a, b, acc[nt], 0, 0, 0);
        }
    }

    int rr = rbase + kgrp * 4;
#pragma unroll
    for (int nt = 0; nt < 8; ++nt) {
#pragma unroll
        for (int j = 0; j < 4; ++j) {
            int r = r0 + rr + j;
            if (r < n_rows) X[(size_t)r * D + nt * 16 + arow] = f2b(acc[nt][j]);
        }
    }
}

// ---- CSR build ----
__global__ void hist_kernel(const int* __restrict__ dst, int* __restrict__ counts, int n_edges) {
    int stride = gridDim.x * blockDim.x;
    for (int e = blockIdx.x * blockDim.x + threadIdx.x; e < n_edges; e += stride)
        atomicAdd(&counts[dst[e]], 1);
}

__global__ void scanA_kernel(const int* __restrict__ counts, int* __restrict__ rowptr,
                             int* __restrict__ blocksums, int n) {
    __shared__ int smem[SCAN_TPB];
    int b = blockIdx.x, t = threadIdx.x;
    int i0 = b * SCAN_CHUNK + t * SCAN_EPT;
    int e[SCAN_EPT];
#pragma unroll
    for (int j = 0; j < SCAN_EPT; ++j) {
        int i = i0 + j;
        e[j] = (i < n) ? counts[i] : 0;
    }
#pragma unroll
    for (int j = 1; j < SCAN_EPT; ++j) e[j] += e[j - 1];
    smem[t] = e[SCAN_EPT - 1];
    __syncthreads();
    for (int off = 1; off < SCAN_TPB; off <<= 1) {
        int u = (t >= off) ? smem[t - off] : 0;
        __syncthreads();
        smem[t] += u;
        __syncthreads();
    }
    int excl = t ? smem[t - 1] : 0;
#pragma unroll
    for (int j = 0; j < SCAN_EPT; ++j) {
        int i = i0 + j;
        if (i < n) rowptr[i + 1] = excl + e[j];
    }
    if (t == SCAN_TPB - 1) blocksums[b] = smem[t];
    if (b == 0 && t == 0) rowptr[0] = 0;
}

__global__ void scanC_kernel(int* __restrict__ rowptr, int* __restrict__ cursor,
                             const int* __restrict__ blocksums, int n) {
    __shared__ int off_s;
    int b = blockIdx.x, t = threadIdx.x;
    if (t == 0) {
        int a = 0;
        for (int i = 0; i < b; ++i) a += blocksums[i];
        off_s = a;
    }
    __syncthreads();
    int off = off_s;
    int i0 = b * SCAN_CHUNK + t * SCAN_EPT;
#pragma unroll
    for (int j = 0; j < SCAN_EPT; ++j) {
        int i = i0 + j;
        if (i < n) {
            int v = rowptr[i + 1] + off;
            rowptr[i + 1] = v;
            if (i + 1 < n) cursor[i + 1] = v;
        }
    }
    if (b == 0 && t == 0) cursor[0] = 0;
}

__global__ void fill_kernel(const int* __restrict__ src, const int* __restrict__ dst,
                            int* __restrict__ cursor, int* __restrict__ srcs, int n_edges) {
    int stride = gridDim.x * blockDim.x;
    for (int e = blockIdx.x * blockDim.x + threadIdx.x; e < n_edges; e += stride) {
        int pos = atomicAdd(&cursor[dst[e]], 1);
        srcs[pos] = src[e];
    }
}

// ---- gather + fused pool: Hb[n]=bf16(relu(...)); hg_next[g] += relu fp32 ----
__global__ __launch_bounds__(256) void gather_pool_kernel(
        const unsigned short* __restrict__ Xb,
        const int* __restrict__ rowptr, const int* __restrict__ srcs,
        const int* __restrict__ gids, const float4* __restrict__ ctxgW4,
        unsigned short* __restrict__ Hb, float* __restrict__ hg_next, int n_nodes) {
    __shared__ float pool_lds[GNODES][D];      // 4 KB
    __shared__ int g_lds[GNODES];
    int w = threadIdx.x >> 5;
    int q = threadIdx.x & 31;
    int n = blockIdx.x * GNODES + w;
    bool active = (n < n_nodes);
    float ax = 0.f, ay = 0.f, az = 0.f, aw = 0.f;
    int g = -1;
    if (active) {
        g = gids[n];
        int beg = rowptr[n], end = rowptr[n + 1];
        ushort4 a = *(const ushort4*)(Xb + (size_t)n * D + q * 4);
        float4 c = ctxgW4[(size_t)g * 32 + q];
        ax = b2f(a.x) + c.x; ay = b2f(a.y) + c.y;
        az = b2f(a.z) + c.z; aw = b2f(a.w) + c.w;
        int e = beg;
        for (; e + 4 <= end; e += 4) {
            int s0 = srcs[e], s1 = srcs[e + 1], s2 = srcs[e + 2], s3 = srcs[e + 3];
            ushort4 v0 = *(const ushort4*)(Xb + (size_t)s0 * D + q * 4);
            ushort4 v1 = *(const ushort4*)(Xb + (size_t)s1 * D + q * 4);
            ushort4 v2 = *(const ushort4*)(Xb + (size_t)s2 * D + q * 4);
            ushort4 v3 = *(const ushort4*)(Xb + (size_t)s3 * D + q * 4);
            ax += (b2f(v0.x) + b2f(v1.x)) + (b2f(v2.x) + b2f(v3.x));
            ay += (b2f(v0.y) + b2f(v1.y)) + (b2f(v2.y) + b2f(v3.y));
            az += (b2f(v0.z) + b2f(v1.z)) + (b2f(v2.z) + b2f(v3.z));
            aw += (b2f(v0.w) + b2f(v1.w)) + (b2f(v2.w) + b2f(v3.w));
        }
        for (; e < end; ++e) {
            ushort4 v = *(const ushort4*)(Xb + (size_t)srcs[e] * D + q * 4);
            ax += b2f(v.x); ay += b2f(v.y); az += b2f(v.z); aw += b2f(v.w);
        }
        ax = fmaxf(ax, 0.f); ay = fmaxf(ay, 0.f);
        az = fmaxf(az, 0.f); aw = fmaxf(aw, 0.f);
        ushort4 o;
        o.x = f2b(ax); o.y = f2b(ay); o.z = f2b(az); o.w = f2b(aw);
        *(ushort4*)(Hb + (size_t)n * D + q * 4) = o;
    }
    if (q == 0) g_lds[w] = g;
    pool_lds[w][q * 4 + 0] = ax;
    pool_lds[w][q * 4 + 1] = ay;
    pool_lds[w][q * 4 + 2] = az;
    pool_lds[w][q * 4 + 3] = aw;
    __syncthreads();
    int gw = g_lds[w];
    bool leader = (gw >= 0) && (w == 0 || g_lds[w - 1] != gw);
    if (leader) {
        float s0 = 0.f, s1 = 0.f, s2 = 0.f, s3 = 0.f;
        for (int w2 = w; w2 < GNODES && g_lds[w2] == gw; ++w2) {
            s0 += pool_lds[w2][q * 4 + 0];
            s1 += pool_lds[w2][q * 4 + 1];
            s2 += pool_lds[w2][q * 4 + 2];
            s3 += pool_lds[w2][q * 4 + 3];
        }
        atomicAdd(&hg_next[gw * D + q * 4 + 0], s0);
        atomicAdd(&hg_next[gw * D + q * 4 + 1], s1);
        atomicAdd(&hg_next[gw * D + q * 4 + 2], s2);
        atomicAdd(&hg_next[gw * D + q * 4 + 3], s3);
    }
}

// ---- W (fp32, KxN) -> WT (bf16, NxK), 3 layers in one dispatch ----
__global__ void wconv_kernel(const float* __restrict__ W0, const float* __restrict__ W1,
                             const float* __restrict__ W2, unsigned short* __restrict__ WTb) {
    const float* W = blockIdx.y == 0 ? W0 : (blockIdx.y == 1 ? W1 : W2);
    unsigned short* WT = WTb + blockIdx.y * (D * D);
    int idx = blockIdx.x * 256 + threadIdx.x;
    int n = idx >> 7, k = idx & 127;
    WT[n * D + k] = f2b(W[k * D + n]);
}

// ---- head ----
__global__ void head_kernel(const float* __restrict__ hg,
                            const float* __restrict__ fc1W, const float* __restrict__ fc1b,
                            const float* __restrict__ fc2W, const float* __restrict__ fc2b,
                            float* __restrict__ out) {
    __shared__ float row[D];
    __shared__ float hfc[D];
    int g = blockIdx.x, t = threadIdx.x;
    row[t] = hg[g * D + t];
    __syncthreads();
    float acc = fc1b[t];
#pragma unroll 4
    for (int k = 0; k < D; ++k) acc = fmaf(row[k], fc1W[k * D + t], acc);
    hfc[t] = fmaxf(acc, 0.f);
    __syncthreads();
    if (t < NACT) {
        float o = fc2b[t];
#pragma unroll 4
        for (int k = 0; k < D; ++k) o = fmaf(hfc[k], fc2W[k * NACT + t], o);
        out[g * NACT + t] = o;
    }
}

extern "C" void kernel_launch(void* const* d_in, const int* in_sizes, int n_in,
                              void* d_out, int out_size, void* d_ws, size_t ws_size,
                              hipStream_t stream) {
    const float* inputs     = (const float*)d_in[0];
    const int*   src        = (const int*)d_in[1];
    const int*   dst        = (const int*)d_in[2];
    const int*   graph_ids  = (const int*)d_in[3];
    const float* init_feats = (const float*)d_in[4];
    const int*   init_gids  = (const int*)d_in[5];
    const float* lead_feats = (const float*)d_in[6];
    const int*   lead_gids  = (const int*)d_in[7];
    const float* Wmat[3] = { (const float*)d_in[8], (const float*)d_in[10], (const float*)d_in[12] };
    const float* bvec[3] = { (const float*)d_in[9], (const float*)d_in[11], (const float*)d_in[13] };
    const float* fc1W = (const float*)d_in[14];
    const float* fc1b = (const float*)d_in[15];
    const float* fc2W = (const float*)d_in[16];
    const float* fc2b = (const float*)d_in[17];
    float* out = (float*)d_out;

    const int n_nodes = in_sizes[0] / D;
    const int n_edges = in_sizes[1];

    // ---- workspace layout (zero region first) ----
    unsigned char* p = (unsigned char*)d_ws;
    float* ctx    = (float*)p;                          p += NGRAPH * D * sizeof(float);
    float* hg     = (float*)p;                          p += 4 * NGRAPH * D * sizeof(float);
    int*   counts = (int*)p;                            p += (size_t)n_nodes * sizeof(int);
    size_t zero_bytes = (size_t)(p - (unsigned char*)d_ws);
    int*   rowptr = (int*)p;                            p += ((size_t)n_nodes + 1) * sizeof(int);
    int*   blocksums = (int*)p;                         p += 64 * sizeof(int);
    float* ctxgW  = (float*)p;                          p += NGRAPH * D * sizeof(float);
    int*   srcs   = (int*)p;                            p += (size_t)n_edges * sizeof(int);
    p = (unsigned char*)(((uintptr_t)p + 15) & ~(uintptr_t)15);
    unsigned short* Hbf = (unsigned short*)p;           p += (size_t)n_nodes * D * sizeof(short);
    unsigned short* Xbf = (unsigned short*)p;           p += (size_t)n_nodes * D * sizeof(short);
    unsigned short* WTb = (unsigned short*)p;           p += 3 * D * D * sizeof(short);

    const int pool_blocks = (n_nodes + POOL_CHUNK - 1) / POOL_CHUNK;
    const int mm_blocks = (n_nodes + 63) / 64;
    const int scan_blocks = (n_nodes + SCAN_CHUNK - 1) / SCAN_CHUNK;
    const int gather_blocks = (n_nodes + GNODES - 1) / GNODES;

    hipMemsetAsync(ctx, 0, zero_bytes, stream);

    // ---- CSR build ----
    hist_kernel<<<1024, 256, 0, stream>>>(dst, counts, n_edges);
    scanA_kernel<<<scan_blocks, SCAN_TPB, 0, stream>>>(counts, rowptr, blocksums, n_nodes);
    scanC_kernel<<<scan_blocks, SCAN_TPB, 0, stream>>>(rowptr, counts, blocksums, n_nodes);
    fill_kernel<<<1024, 256, 0, stream>>>(src, dst, counts, srcs, n_edges);

    // ---- W -> bf16 W^T ----
    wconv_kernel<<<dim3(64, 3), 256, 0, stream>>>(Wmat[0], Wmat[1], Wmat[2], WTb);

    // ---- pools: init->ctx, lead->ctx, inputs->hg0 (+ bf16 conversion of inputs) ----
    pool3_kernel<<<dim3(pool_blocks, 3), D, 0, stream>>>(
        init_feats, init_gids, ctx, lead_feats, lead_gids, ctx,
        inputs, graph_ids, hg, Hbf, n_nodes);

    for (int layer = 0; layer < 3; ++layer) {
        float* hgL = hg + layer * NGRAPH * D;
        mm_ctxw_kernel<<<mm_blocks + NGRAPH / 2, 256, 0, stream>>>(
            Hbf, WTb + layer * D * D, Xbf,
            hgL, ctx, Wmat[layer], bvec[layer], ctxgW, n_nodes, mm_blocks);
        gather_pool_kernel<<<gather_blocks, 256, 0, stream>>>(
            Xbf, rowptr, srcs, graph_ids, (const float4*)ctxgW,
            Hbf, hg + (layer + 1) * NGRAPH * D, n_nodes);
    }

    // ---- head ----
    head_kernel<<<NGRAPH, D, 0, stream>>>(hg + 3 * NGRAPH * D, fc1W, fc1b, fc2W, fc2b, out);
}